// Round 4
// baseline (422.892 us; speedup 1.0000x reference)
//
#include <hip/hip_runtime.h>
#include <math.h>

// ---------------------------------------------------------------------------
// GATRec restructured:
//   a_src = h·attS = x·(W@attS)  -> logits from x directly
//   out   = sum(alpha * (x@W))   = (sum(alpha * x)) @ W   (aggregate first)
//   Edge weights precomputed edge-parallel (scatter / edge_w2);
//   agg loops are pure weighted-sum with scalarized addressing.
// ---------------------------------------------------------------------------

typedef float f32x4 __attribute__((ext_vector_type(4)));
typedef short s16x8 __attribute__((ext_vector_type(8)));

static __device__ __forceinline__ short f2bf(float f) {
    unsigned u = __builtin_bit_cast(unsigned, f);
    u = (u + 0x7fff + ((u >> 16) & 1)) >> 16;  // RNE
    return (short)u;
}
static __device__ __forceinline__ float bf2f(unsigned short u) {
    unsigned v = ((unsigned)u) << 16;
    return __builtin_bit_cast(float, v);
}

// ------------------------------- graph build -------------------------------

__global__ void hist_kernel(const int* __restrict__ ei, int E, int ET,
                            int* __restrict__ cnt) {
    int e = blockIdx.x * blockDim.x + threadIdx.x;
    if (e >= ET) return;
    int d = (e < E) ? ei[E + e] : (e - E);
    atomicAdd(&cnt[d], 1);
}

__global__ __launch_bounds__(256) void scan_blocks_kernel(
    const int* __restrict__ cnt, int* __restrict__ offs,
    int* __restrict__ bsums, int n) {
    __shared__ int sdata[256];
    int base = blockIdx.x * 4096 + threadIdx.x * 16;
    int vals[16];
    int tsum = 0;
#pragma unroll
    for (int i = 0; i < 16; ++i) {
        int idx = base + i;
        int v = (idx < n) ? cnt[idx] : 0;
        vals[i] = v;
        tsum += v;
    }
    sdata[threadIdx.x] = tsum;
    __syncthreads();
    for (int off = 1; off < 256; off <<= 1) {
        int v = (threadIdx.x >= off) ? sdata[threadIdx.x - off] : 0;
        __syncthreads();
        sdata[threadIdx.x] += v;
        __syncthreads();
    }
    int run = sdata[threadIdx.x] - tsum;
    if (threadIdx.x == 255) bsums[blockIdx.x] = sdata[255];
#pragma unroll
    for (int i = 0; i < 16; ++i) {
        int idx = base + i;
        if (idx < n) offs[idx] = run;
        run += vals[i];
    }
}

__global__ void scan_small_kernel(int* bsums, int nb) {
    if (blockIdx.x == 0 && threadIdx.x == 0) {
        int run = 0;
        for (int i = 0; i < nb; ++i) {
            int v = bsums[i];
            bsums[i] = run;
            run += v;
        }
    }
}

__global__ void scan_add_kernel(int* __restrict__ offs, int* __restrict__ cursor,
                                const int* __restrict__ bsums, int n, int total) {
    int idx = blockIdx.x * blockDim.x + threadIdx.x;
    if (idx < n) {
        int v = offs[idx] + bsums[idx >> 12];
        offs[idx] = v;
        cursor[idx] = v;
    }
    if (idx == 0) offs[n] = total;
}

// scatter + layer-1 edge weights (as1/ad1 ready by now)
__global__ void scatter_kernel(const int* __restrict__ ei, int E, int ET,
                               const float* __restrict__ as1,
                               const float* __restrict__ ad1,
                               int* __restrict__ cursor, int* __restrict__ csr,
                               int* __restrict__ dstA, float* __restrict__ wts1) {
    int e = blockIdx.x * blockDim.x + threadIdx.x;
    if (e >= ET) return;
    int s, d;
    if (e < E) { s = ei[e]; d = ei[E + e]; } else { s = e - E; d = e - E; }
    int pos = atomicAdd(&cursor[d], 1);
    csr[pos] = s;
    dstA[pos] = d;
    float4 as = *reinterpret_cast<const float4*>(as1 + (size_t)s * 4);
    float4 ad = *reinterpret_cast<const float4*>(ad1 + (size_t)d * 4);
    float4 w;
    float lg;
    lg = as.x + ad.x; lg = (lg >= 0.f) ? lg : 0.2f * lg; w.x = __expf(lg);
    lg = as.y + ad.y; lg = (lg >= 0.f) ? lg : 0.2f * lg; w.y = __expf(lg);
    lg = as.z + ad.z; lg = (lg >= 0.f) ? lg : 0.2f * lg; w.z = __expf(lg);
    lg = as.w + ad.w; lg = (lg >= 0.f) ? lg : 0.2f * lg; w.w = __expf(lg);
    *reinterpret_cast<float4*>(wts1 + (size_t)pos * 4) = w;
}

// layer-2 edge weights (after gemm_mid produced as2/ad2)
__global__ void edge_w2_kernel(const int* __restrict__ csr,
                               const int* __restrict__ dstA,
                               const float* __restrict__ as2,
                               const float* __restrict__ ad2,
                               float* __restrict__ wts2, int ET) {
    int p = blockIdx.x * blockDim.x + threadIdx.x;
    if (p >= ET) return;
    float lg = as2[csr[p]] + ad2[dstA[p]];
    lg = (lg >= 0.f) ? lg : 0.2f * lg;
    wts2[p] = __expf(lg);
}

// ---------------------------------------------------------------------------
// prep_attv: attv1s[k][h] = sum_c W1[k][h*64+c]*attS1[h][c]   (64x4)
//            attv2s[k]    = sum_c W2[k][c]*attS2[c]           (256)
// ---------------------------------------------------------------------------
__global__ void prep_attv_kernel(const float* __restrict__ W1,
                                 const float* __restrict__ attS1,
                                 const float* __restrict__ attD1,
                                 const float* __restrict__ W2,
                                 const float* __restrict__ attS2,
                                 const float* __restrict__ attD2,
                                 float* __restrict__ attv1s, float* __restrict__ attv1d,
                                 float* __restrict__ attv2s, float* __restrict__ attv2d) {
    int t = threadIdx.x;
    {
        int k = t >> 2, h = t & 3;
        float ss = 0.f, sd = 0.f;
        for (int c = 0; c < 64; ++c) {
            float w = W1[k * 256 + h * 64 + c];
            ss += w * attS1[h * 64 + c];
            sd += w * attD1[h * 64 + c];
        }
        attv1s[k * 4 + h] = ss;
        attv1d[k * 4 + h] = sd;
    }
    {
        float ss = 0.f, sd = 0.f;
        for (int c = 0; c < 64; ++c) {
            float w = W2[t * 64 + c];
            ss += w * attS2[c];
            sd += w * attD2[c];
        }
        attv2s[t] = ss;
        attv2d[t] = sd;
    }
}

// ---------------------------------------------------------------------------
// cast_att: xb[n][64] = bf16(x[n]); as1[n][h] = x[n]·attv1s[:,h]; same ad1.
// ---------------------------------------------------------------------------
__global__ __launch_bounds__(256) void cast_att_kernel(
    const float* __restrict__ xu, const float* __restrict__ xi, int NU, int N,
    const float* __restrict__ attv1s, const float* __restrict__ attv1d,
    unsigned short* __restrict__ xb, float* __restrict__ as1,
    float* __restrict__ ad1) {
    int wv = threadIdx.x >> 6, lane = threadIdx.x & 63;
    int n = blockIdx.x * 4 + wv;
    if (n >= N) return;
    float v = (n < NU) ? xu[(size_t)n * 64 + lane] : xi[(size_t)(n - NU) * 64 + lane];
    xb[(size_t)n * 64 + lane] = (unsigned short)f2bf(v);
    float4 avS = *reinterpret_cast<const float4*>(attv1s + lane * 4);
    float4 avD = *reinterpret_cast<const float4*>(attv1d + lane * 4);
    float s0 = v * avS.x, s1 = v * avS.y, s2 = v * avS.z, s3 = v * avS.w;
    float d0 = v * avD.x, d1 = v * avD.y, d2 = v * avD.z, d3 = v * avD.w;
#pragma unroll
    for (int msk = 32; msk; msk >>= 1) {
        s0 += __shfl_xor(s0, msk); s1 += __shfl_xor(s1, msk);
        s2 += __shfl_xor(s2, msk); s3 += __shfl_xor(s3, msk);
        d0 += __shfl_xor(d0, msk); d1 += __shfl_xor(d1, msk);
        d2 += __shfl_xor(d2, msk); d3 += __shfl_xor(d3, msk);
    }
    if (lane == 0) {
        *reinterpret_cast<float4*>(as1 + (size_t)n * 4) = make_float4(s0, s1, s2, s3);
        *reinterpret_cast<float4*>(ad1 + (size_t)n * 4) = make_float4(d0, d1, d2, d3);
    }
}

// ---------------------------------------------------------------------------
// AGG1: y[n][h][c] = (sum_e w_e * x[src_e][c]) / sum_e w_e, bf16 out.
// Wave per node (n scalarized); lane owns (h = lane>>4, 4 channels).
// Pure weighted-sum: weights precomputed in wts1.
// ---------------------------------------------------------------------------
__global__ __launch_bounds__(256) void agg1_kernel(
    const unsigned short* __restrict__ xb, const float* __restrict__ wts1,
    const int* __restrict__ offs, const int* __restrict__ csr,
    unsigned short* __restrict__ yb, int N) {
    int wv = threadIdx.x >> 6, lane = threadIdx.x & 63;
    int n = __builtin_amdgcn_readfirstlane(blockIdx.x * 4 + wv);
    if (n >= N) return;
    int h = lane >> 4, c4 = (lane & 15) * 4;
    int beg = offs[n], end = offs[n + 1];
    float ss = 0.f, a0 = 0.f, a1 = 0.f, a2 = 0.f, a3 = 0.f;

    // pipeline: csr 2 ahead, (w, x) 1 ahead
    int s0 = csr[beg];
    float wC = wts1[(size_t)beg * 4 + h];
    ushort4 hC = *reinterpret_cast<const ushort4*>(xb + (size_t)s0 * 64 + c4);
    int o1 = (beg + 1 < end) ? beg + 1 : beg;
    int sN = csr[o1];

    for (int o = beg; o < end; ++o) {
        int o2 = (o + 2 < end) ? o + 2 : beg;
        int sN2 = csr[o2];
        int on = (o + 1 < end) ? o + 1 : beg;
        float wN = wts1[(size_t)on * 4 + h];
        ushort4 hN = *reinterpret_cast<const ushort4*>(xb + (size_t)sN * 64 + c4);
        ss += wC;
        a0 += wC * bf2f(hC.x);
        a1 += wC * bf2f(hC.y);
        a2 += wC * bf2f(hC.z);
        a3 += wC * bf2f(hC.w);
        wC = wN; hC = hN; sN = sN2;
    }
    float inv = 1.f / (ss + 1e-16f);
    ushort4 ov;
    ov.x = (unsigned short)f2bf(a0 * inv);
    ov.y = (unsigned short)f2bf(a1 * inv);
    ov.z = (unsigned short)f2bf(a2 * inv);
    ov.w = (unsigned short)f2bf(a3 * inv);
    *reinterpret_cast<ushort4*>(yb + (size_t)n * 256 + h * 64 + c4) = ov;
}

// ---------------------------------------------------------------------------
// GEMM-mid (MFMA): x2[n][j] = ELU( y[n][head(j)][:] · W1[:][j] + b1[j] )
// Fused epilogue: as2[n] = x2[n]·attv2s, ad2[n] = x2[n]·attv2d.
// ---------------------------------------------------------------------------
__global__ __launch_bounds__(256, 1) void gemm_mid_mfma(
    const unsigned short* __restrict__ yb, int N, const float* __restrict__ W1,
    const float* __restrict__ b1, const float* __restrict__ attv2s,
    const float* __restrict__ attv2d, unsigned short* __restrict__ x2,
    float* __restrict__ as2, float* __restrict__ ad2) {
    int t = threadIdx.x;
    int wv = t >> 6;
    int l = t & 63;
    int l15 = l & 15;
    int lg = l >> 4;

    s16x8 Bfr[16][2];
#pragma unroll
    for (int ct = 0; ct < 16; ++ct)
#pragma unroll
        for (int ks = 0; ks < 2; ++ks) {
            s16x8 f;
#pragma unroll
            for (int j = 0; j < 8; ++j)
                f[j] = f2bf(W1[(size_t)(ks * 32 + lg * 8 + j) * 256 + ct * 16 + l15]);
            Bfr[ct][ks] = f;
        }

    int wid = blockIdx.x * 4 + wv;
    int ntile = (N + 15) >> 4;
    int stride = gridDim.x * 4;
    for (int tile = wid; tile < ntile; tile += stride) {
        int rbase = tile * 16;
        int arow = rbase + l15;
        if (arow >= N) arow = N - 1;
        const unsigned short* yp = yb + (size_t)arow * 256;
        s16x8 Afr[4][2];
#pragma unroll
        for (int hd = 0; hd < 4; ++hd)
#pragma unroll
            for (int ks = 0; ks < 2; ++ks)
                Afr[hd][ks] = *reinterpret_cast<const s16x8*>(yp + hd * 64 + ks * 32 + lg * 8);
        f32x4 acc[16];
#pragma unroll
        for (int ct = 0; ct < 16; ++ct) acc[ct] = (f32x4){0.f, 0.f, 0.f, 0.f};
#pragma unroll
        for (int ct = 0; ct < 16; ++ct) {
            int hd = ct >> 2;
            acc[ct] = __builtin_amdgcn_mfma_f32_16x16x32_bf16(Afr[hd][0], Bfr[ct][0], acc[ct], 0, 0, 0);
            acc[ct] = __builtin_amdgcn_mfma_f32_16x16x32_bf16(Afr[hd][1], Bfr[ct][1], acc[ct], 0, 0, 0);
        }
        int r0 = rbase + lg * 4;
        float rs[4] = {0.f, 0.f, 0.f, 0.f};
        float rd[4] = {0.f, 0.f, 0.f, 0.f};
#pragma unroll
        for (int ct = 0; ct < 16; ++ct) {
            int col = ct * 16 + l15;
            float bv = b1[col];
            float avs = attv2s[col];
            float avd = attv2d[col];
#pragma unroll
            for (int i = 0; i < 4; ++i) {
                float v = acc[ct][i] + bv;
                v = (v > 0.f) ? v : __expf(v) - 1.f;
                rs[i] += v * avs;
                rd[i] += v * avd;
                int r = r0 + i;
                if (r < N)
                    x2[(size_t)r * 256 + col] = (unsigned short)f2bf(v);
            }
        }
#pragma unroll
        for (int i = 0; i < 4; ++i) {
#pragma unroll
            for (int msk = 8; msk; msk >>= 1) {
                rs[i] += __shfl_xor(rs[i], msk);
                rd[i] += __shfl_xor(rd[i], msk);
            }
            int r = r0 + i;
            if (l15 == 0 && r < N) {
                as2[r] = rs[i];
                ad2[r] = rd[i];
            }
        }
    }
}

// ---------------------------------------------------------------------------
// GEMM2 (MFMA): h2[N,64] = x2[N,256] @ W2[256,64], bf16 in/out.
// ---------------------------------------------------------------------------
__global__ __launch_bounds__(256, 2) void gemm2_mfma(
    const unsigned short* __restrict__ x2, int N, const float* __restrict__ W2,
    unsigned short* __restrict__ h2) {
    int t = threadIdx.x;
    int wv = t >> 6;
    int l = t & 63;
    int l15 = l & 15;
    int lg = l >> 4;

    s16x8 Bfr[8][4];
#pragma unroll
    for (int ks = 0; ks < 8; ++ks)
#pragma unroll
        for (int ct = 0; ct < 4; ++ct) {
            s16x8 f;
#pragma unroll
            for (int j = 0; j < 8; ++j)
                f[j] = f2bf(W2[(size_t)(ks * 32 + lg * 8 + j) * 64 + ct * 16 + l15]);
            Bfr[ks][ct] = f;
        }

    int wid = blockIdx.x * 4 + wv;
    int ntile = (N + 15) >> 4;
    int stride = gridDim.x * 4;
    for (int tile = wid; tile < ntile; tile += stride) {
        int rbase = tile * 16;
        int arow = rbase + l15;
        if (arow >= N) arow = N - 1;
        const unsigned short* xp = x2 + (size_t)arow * 256;
        f32x4 acc[4];
#pragma unroll
        for (int ct = 0; ct < 4; ++ct) acc[ct] = (f32x4){0.f, 0.f, 0.f, 0.f};
#pragma unroll
        for (int ks = 0; ks < 8; ++ks) {
            s16x8 Afr = *reinterpret_cast<const s16x8*>(xp + ks * 32 + lg * 8);
#pragma unroll
            for (int ct = 0; ct < 4; ++ct)
                acc[ct] = __builtin_amdgcn_mfma_f32_16x16x32_bf16(Afr, Bfr[ks][ct], acc[ct], 0, 0, 0);
        }
        int r0 = rbase + lg * 4;
#pragma unroll
        for (int ct = 0; ct < 4; ++ct)
#pragma unroll
            for (int i = 0; i < 4; ++i) {
                int r = r0 + i;
                if (r < N)
                    h2[(size_t)r * 64 + ct * 16 + l15] = (unsigned short)f2bf(acc[ct][i]);
            }
    }
}

// ---------------------------------------------------------------------------
// AGG2: out[n] = (sum_e w_e * h2[src_e]) / sum_e w_e + b2, f32 out.
// ---------------------------------------------------------------------------
__global__ __launch_bounds__(256) void agg2_kernel(
    const unsigned short* __restrict__ h2, const float* __restrict__ wts2,
    const int* __restrict__ offs, const int* __restrict__ csr,
    const float* __restrict__ b2, float* __restrict__ out, int N) {
    int wv = threadIdx.x >> 6, lane = threadIdx.x & 63;
    int n = __builtin_amdgcn_readfirstlane(blockIdx.x * 4 + wv);
    if (n >= N) return;
    int beg = offs[n], end = offs[n + 1];
    float ss = 0.f, acc = 0.f;

    int s0 = csr[beg];
    float wC = wts2[beg];
    unsigned short hC = h2[(size_t)s0 * 64 + lane];
    int o1 = (beg + 1 < end) ? beg + 1 : beg;
    int sN = csr[o1];

    for (int o = beg; o < end; ++o) {
        int o2 = (o + 2 < end) ? o + 2 : beg;
        int sN2 = csr[o2];
        int on = (o + 1 < end) ? o + 1 : beg;
        float wN = wts2[on];
        unsigned short hN = h2[(size_t)sN * 64 + lane];
        ss += wC;
        acc += wC * bf2f(hC);
        wC = wN; hC = hN; sN = sN2;
    }
    out[(size_t)n * 64 + lane] = acc / (ss + 1e-16f) + b2[lane];
}

// ---------------------------------------------------------------------------

extern "C" void kernel_launch(void* const* d_in, const int* in_sizes, int n_in,
                              void* d_out, int out_size, void* d_ws, size_t ws_size,
                              hipStream_t stream) {
    const int* ei = (const int*)d_in[0];
    const float* xu = (const float*)d_in[1];
    const float* xi = (const float*)d_in[2];
    const float* W1 = (const float*)d_in[3];
    const float* attS1 = (const float*)d_in[4];
    const float* attD1 = (const float*)d_in[5];
    const float* b1 = (const float*)d_in[6];
    const float* W2 = (const float*)d_in[7];
    const float* attS2 = (const float*)d_in[8];
    const float* attD2 = (const float*)d_in[9];
    const float* b2 = (const float*)d_in[10];
    float* out = (float*)d_out;

    const int E = in_sizes[0] / 2;
    const int NU = in_sizes[1] / 64;
    const int NI = in_sizes[2] / 64;
    const int N = NU + NI;
    const int ET = E + N;

    char* p = (char*)d_ws;
    auto carve = [&](size_t bytes) {
        void* r = (void*)p;
        p += (bytes + 255) & ~(size_t)255;
        return r;
    };
    unsigned short* xb = (unsigned short*)carve((size_t)N * 64 * 2);   // 14 MB
    unsigned short* yb = (unsigned short*)carve((size_t)N * 256 * 2);  // 56 MB
    unsigned short* x2 = (unsigned short*)carve((size_t)N * 256 * 2);  // 56 MB
    float* as1 = (float*)carve((size_t)N * 4 * 4);
    float* ad1 = (float*)carve((size_t)N * 4 * 4);
    float* as2 = (float*)carve((size_t)N * 4);
    float* ad2 = (float*)carve((size_t)N * 4);
    float* attv1s = (float*)carve(256 * 4);
    float* attv1d = (float*)carve(256 * 4);
    float* attv2s = (float*)carve(256 * 4);
    float* attv2d = (float*)carve(256 * 4);
    int* offs = (int*)carve((size_t)(N + 1) * 4);
    int* cursor = (int*)carve((size_t)N * 4);
    int* csr = (int*)carve((size_t)ET * 4);
    int* dstA = (int*)carve((size_t)ET * 4);
    float* wts1 = (float*)carve((size_t)ET * 4 * 4);  // 17.8 MB
    float* wts2 = (float*)carve((size_t)ET * 4);      // 4.4 MB
    int* bsums = (int*)carve(64 * 4);
    unsigned short* h2 = yb;  // yb dead after gemm_mid

    // --- small precomputes ---
    prep_attv_kernel<<<1, 256, 0, stream>>>(W1, attS1, attD1, W2, attS2, attD2,
                                            attv1s, attv1d, attv2s, attv2d);
    cast_att_kernel<<<(N + 3) / 4, 256, 0, stream>>>(xu, xi, NU, N, attv1s, attv1d,
                                                     xb, as1, ad1);

    // --- build CSR (grouped by dst) + layer-1 edge weights ---
    hipMemsetAsync(cursor, 0, (size_t)N * 4, stream);
    {
        int grid = (ET + 255) / 256;
        hist_kernel<<<grid, 256, 0, stream>>>(ei, E, ET, cursor);
    }
    {
        int nsb = (N + 4095) / 4096;
        scan_blocks_kernel<<<nsb, 256, 0, stream>>>(cursor, offs, bsums, N);
        scan_small_kernel<<<1, 64, 0, stream>>>(bsums, nsb);
        int grid = (N + 255) / 256;
        scan_add_kernel<<<grid, 256, 0, stream>>>(offs, cursor, bsums, N, ET);
    }
    {
        int grid = (ET + 255) / 256;
        scatter_kernel<<<grid, 256, 0, stream>>>(ei, E, ET, as1, ad1, cursor, csr,
                                                 dstA, wts1);
    }

    // --- layer 1: aggregate x, then GEMM+ELU ---
    agg1_kernel<<<(N + 3) / 4, 256, 0, stream>>>(xb, wts1, offs, csr, yb, N);
    gemm_mid_mfma<<<512, 256, 0, stream>>>(yb, N, W1, b1, attv2s, attv2d, x2, as2, ad2);

    // --- layer 2: edge weights, GEMM, aggregate h2 ---
    {
        int grid = (ET + 255) / 256;
        edge_w2_kernel<<<grid, 256, 0, stream>>>(csr, dstA, as2, ad2, wts2, ET);
    }
    gemm2_mfma<<<512, 256, 0, stream>>>(x2, N, W2, h2);
    agg2_kernel<<<(N + 3) / 4, 256, 0, stream>>>(h2, wts2, offs, csr, b2, out, N);
}